// Round 4
// baseline (47.945 us; speedup 1.0000x reference)
//
#include <hip/hip_runtime.h>

// One thread per batch (3x3 complex). 256 batches/block, 4 waves.
// Inputs: per-lane DIRECT global loads (9 consecutive f32 per matrix; L1
// serves the stride-36 line re-touches, HBM traffic unchanged).
// Output: wave-private LDS staging (18 KB/block) -> full-line float4
// nontemporal stores. No __syncthreads() anywhere (in-wave DS ordering only).
// Two-phase compute (E from V first, then U0 product) keeps VGPR pressure
// low; __launch_bounds__(256,5) caps VGPR at 96 -> 5 waves/SIMD.

#define BPB 256

typedef float f32x4 __attribute__((ext_vector_type(4)));  // native vec for nontemporal

__global__ __launch_bounds__(256, 5)
void sun_diffuse_kernel(const float* __restrict__ U0_re, const float* __restrict__ U0_im,
                        const float* __restrict__ xs,
                        const float* __restrict__ V_re, const float* __restrict__ V_im,
                        float* __restrict__ out, int nb)
{
    __shared__ float sOut[4][1152];            // 64 batches * 18 f32 per wave

    const int tid  = threadIdx.x;
    const int w    = tid >> 6;
    const int lane = tid & 63;
    const int wb0  = blockIdx.x * BPB + w * 64;       // first batch of this wave
    const int nw   = min(max(nb - wb0, 0), 64);       // batches this wave owns

    float outr[9], outi[9];
    if (lane < nw) {
        const size_t mb = (size_t)(wb0 + lane) * 9;
        const size_t xb = (size_t)(wb0 + lane) * 3;

        // ---- phase 1: V and phases -> E = V diag(e^{ix}) V^H ----
        float vr[9], vi[9];
#pragma unroll
        for (int m = 0; m < 9; ++m) { vr[m] = V_re[mb + m]; vi[m] = V_im[mb + m]; }
        float pr[3], pi[3];
#pragma unroll
        for (int k = 0; k < 3; ++k) {
            float s, c;
            __sincosf(xs[xb + k], &s, &c);
            pr[k] = c; pi[k] = s;
        }
        float Er[9], Ei[9];
#pragma unroll
        for (int i = 0; i < 3; ++i) {
#pragma unroll
            for (int j = 0; j < 3; ++j) {
                float er = 0.f, ei = 0.f;
#pragma unroll
                for (int k = 0; k < 3; ++k) {
                    float wr = pr[k] * vr[i * 3 + k] - pi[k] * vi[i * 3 + k];
                    float wi = pr[k] * vi[i * 3 + k] + pi[k] * vr[i * 3 + k];
                    er += wr * vr[j * 3 + k] + wi * vi[j * 3 + k];
                    ei += wi * vr[j * 3 + k] - wr * vi[j * 3 + k];
                }
                Er[i * 3 + j] = er; Ei[i * 3 + j] = ei;
            }
        }

        // ---- phase 2: U0 -> Ut = E @ U0 ----
        float ur[9], ui[9];
#pragma unroll
        for (int m = 0; m < 9; ++m) { ur[m] = U0_re[mb + m]; ui[m] = U0_im[mb + m]; }
#pragma unroll
        for (int i = 0; i < 3; ++i) {
#pragma unroll
            for (int j = 0; j < 3; ++j) {
                float r = 0.f, im = 0.f;
#pragma unroll
                for (int k = 0; k < 3; ++k) {
                    r  += Er[i * 3 + k] * ur[k * 3 + j] - Ei[i * 3 + k] * ui[k * 3 + j];
                    im += Er[i * 3 + k] * ui[k * 3 + j] + Ei[i * 3 + k] * ur[k * 3 + j];
                }
                outr[i * 3 + j] = r; outi[i * 3 + j] = im;
            }
        }
    }

    // ---- stage output in this wave's LDS slice, flush coalesced ----
    float* S = sOut[w];
    if (lane < nw) {
#pragma unroll
        for (int m = 0; m < 9; ++m) {
            S[lane * 18 + 2 * m]     = outr[m];
            S[lane * 18 + 2 * m + 1] = outi[m];
        }
    }
    // in-wave DS ordering: reads below are ordered after the writes above

    if (nw == 64) {
        // 64*18 = 1152 f32 = 288 float4; byte base wb0*72 is 16B-aligned
        f32x4* gO = reinterpret_cast<f32x4*>(out + (size_t)wb0 * 18);
        const f32x4* s = reinterpret_cast<const f32x4*>(S);
#pragma unroll
        for (int r = 0; r < 5; ++r) {
            int i = lane + r * 64;                    // 288 = 4*64 + 32
            if (i < 288) __builtin_nontemporal_store(s[i], &gO[i]);
        }
    } else if (nw > 0) {
        for (int i = lane; i < nw * 18; i += 64) out[(size_t)wb0 * 18 + i] = S[i];
    }
}

extern "C" void kernel_launch(void* const* d_in, const int* in_sizes, int n_in,
                              void* d_out, int out_size, void* d_ws, size_t ws_size,
                              hipStream_t stream) {
    const float* U0_re = (const float*)d_in[0];
    const float* U0_im = (const float*)d_in[1];
    const float* xs    = (const float*)d_in[2];
    const float* V_re  = (const float*)d_in[3];
    const float* V_im  = (const float*)d_in[4];
    float* out = (float*)d_out;

    const int nb = in_sizes[2] / 3;
    const int grid = (nb + BPB - 1) / BPB;
    sun_diffuse_kernel<<<grid, 256, 0, stream>>>(U0_re, U0_im, xs, V_re, V_im, out, nb);
}

// Round 5
// 40.065 us; speedup vs baseline: 1.1967x; 1.1967x over previous
//
#include <hip/hip_runtime.h>

// One thread per batch (3x3 complex). 256 batches/block, 4 waves, wave-private
// LDS, zero __syncthreads(). Phase-split LDS reuse cuts LDS to 1344 f32/wave
// (21504 B/block -> 6+ blocks/CU vs 4): stage V+xs -> E -> restage U0 into the
// SAME region (in-wave DS ordering keeps RAW/WAR safe) -> product -> restage
// output -> coalesced float4 flush. U0 is prefetched to registers in the first
// load burst so phase 2 has no HBM round-trip (issue-early/write-late).

#define BPB 256

__global__ __launch_bounds__(256, 6)
void sun_diffuse_kernel(const float* __restrict__ U0_re, const float* __restrict__ U0_im,
                        const float* __restrict__ xs,
                        const float* __restrict__ V_re, const float* __restrict__ V_im,
                        float* __restrict__ out, int nb)
{
    // per-wave slice: buf[1152] (V -> U0 -> out) + xs[192] = 1344 f32 = 5376 B
    __shared__ float smem[4][1344];

    const int tid  = threadIdx.x;
    const int w    = tid >> 6;
    const int lane = tid & 63;
    const int wb0  = blockIdx.x * BPB + w * 64;      // first batch of this wave
    const int nw   = min(max(nb - wb0, 0), 64);      // batches this wave owns
    const bool full = (nw == 64);

    float* S   = smem[w];
    float* sA  = S;            // V_re -> U0_re -> out[0:576]
    float* sB  = S + 576;      // V_im -> U0_im -> out[576:1152]
    float* sxs = S + 1152;

    float4 u0re[3], u0im[3];   // U0 prefetch held in regs across phase 1

    if (full) {
        const float4* gVr = reinterpret_cast<const float4*>(V_re  + (size_t)wb0 * 9);
        const float4* gVi = reinterpret_cast<const float4*>(V_im  + (size_t)wb0 * 9);
        const float4* gUr = reinterpret_cast<const float4*>(U0_re + (size_t)wb0 * 9);
        const float4* gUi = reinterpret_cast<const float4*>(U0_im + (size_t)wb0 * 9);
        float4 vre[3], vim[3], x4;
        // one burst: issue ALL 13 global loads (V, U0, xs) before any wait
#pragma unroll
        for (int r = 0; r < 3; ++r) {
            const int i = lane + r * 64;             // 144 = 2*64 + 16
            if (i < 144) {
                vre[r]  = gVr[i]; vim[r]  = gVi[i];
                u0re[r] = gUr[i]; u0im[r] = gUi[i];
            }
        }
        if (lane < 48) x4 = reinterpret_cast<const float4*>(xs + (size_t)wb0 * 3)[lane];
        // stage V + xs (U0 stays in regs)
#pragma unroll
        for (int r = 0; r < 3; ++r) {
            const int i = lane + r * 64;
            if (i < 144) {
                reinterpret_cast<float4*>(sA)[i] = vre[r];
                reinterpret_cast<float4*>(sB)[i] = vim[r];
            }
        }
        if (lane < 48) reinterpret_cast<float4*>(sxs)[lane] = x4;
    } else {
        for (int i = lane; i < nw * 9; i += 64) {
            sA[i] = V_re[(size_t)wb0 * 9 + i];
            sB[i] = V_im[(size_t)wb0 * 9 + i];
        }
        for (int i = lane; i < nw * 3; i += 64) sxs[i] = xs[(size_t)wb0 * 3 + i];
    }

    // ---- phase 1: E = V diag(e^{ix}) V^H ----
    float Er[9], Ei[9];
    if (lane < nw) {
        float vr[9], vi[9];
#pragma unroll
        for (int m = 0; m < 9; ++m) { vr[m] = sA[lane * 9 + m]; vi[m] = sB[lane * 9 + m]; }
        float pr[3], pi[3];
#pragma unroll
        for (int k = 0; k < 3; ++k) {
            float s, c;
            __sincosf(sxs[lane * 3 + k], &s, &c);
            pr[k] = c; pi[k] = s;
        }
#pragma unroll
        for (int i = 0; i < 3; ++i) {
#pragma unroll
            for (int j = 0; j < 3; ++j) {
                float er = 0.f, ei = 0.f;
#pragma unroll
                for (int k = 0; k < 3; ++k) {
                    float wr = pr[k] * vr[i * 3 + k] - pi[k] * vi[i * 3 + k];
                    float wi = pr[k] * vi[i * 3 + k] + pi[k] * vr[i * 3 + k];
                    er += wr * vr[j * 3 + k] + wi * vi[j * 3 + k];
                    ei += wi * vr[j * 3 + k] - wr * vi[j * 3 + k];
                }
                Er[i * 3 + j] = er; Ei[i * 3 + j] = ei;
            }
        }
    }

    // ---- restage U0 into the SAME region (WAR vs V reads: in-wave DS order) ----
    if (full) {
#pragma unroll
        for (int r = 0; r < 3; ++r) {
            const int i = lane + r * 64;
            if (i < 144) {
                reinterpret_cast<float4*>(sA)[i] = u0re[r];
                reinterpret_cast<float4*>(sB)[i] = u0im[r];
            }
        }
    } else {
        for (int i = lane; i < nw * 9; i += 64) {
            sA[i] = U0_re[(size_t)wb0 * 9 + i];
            sB[i] = U0_im[(size_t)wb0 * 9 + i];
        }
    }

    // ---- phase 2: Ut = E @ U0 ----
    float outr[9], outi[9];
    if (lane < nw) {
        float ur[9], ui[9];
#pragma unroll
        for (int m = 0; m < 9; ++m) { ur[m] = sA[lane * 9 + m]; ui[m] = sB[lane * 9 + m]; }
#pragma unroll
        for (int i = 0; i < 3; ++i) {
#pragma unroll
            for (int j = 0; j < 3; ++j) {
                float r = 0.f, im = 0.f;
#pragma unroll
                for (int k = 0; k < 3; ++k) {
                    r  += Er[i * 3 + k] * ur[k * 3 + j] - Ei[i * 3 + k] * ui[k * 3 + j];
                    im += Er[i * 3 + k] * ui[k * 3 + j] + Ei[i * 3 + k] * ur[k * 3 + j];
                }
                outr[i * 3 + j] = r; outi[i * 3 + j] = im;
            }
        }
    }

    // ---- restage output (18 f32/batch interleaved re/im), coalesced flush ----
    if (lane < nw) {
#pragma unroll
        for (int m = 0; m < 9; ++m) {
            S[lane * 18 + 2 * m]     = outr[m];
            S[lane * 18 + 2 * m + 1] = outi[m];
        }
    }

    if (full) {
        // 64*18 = 1152 f32 = 288 float4; byte base wb0*72 is 16B-aligned
        float4* gO = reinterpret_cast<float4*>(out + (size_t)wb0 * 18);
        const float4* s = reinterpret_cast<const float4*>(S);
#pragma unroll
        for (int r = 0; r < 5; ++r) {
            const int i = lane + r * 64;             // 288 = 4*64 + 32
            if (i < 288) gO[i] = s[i];
        }
    } else if (nw > 0) {
        for (int i = lane; i < nw * 18; i += 64) out[(size_t)wb0 * 18 + i] = S[i];
    }
}

extern "C" void kernel_launch(void* const* d_in, const int* in_sizes, int n_in,
                              void* d_out, int out_size, void* d_ws, size_t ws_size,
                              hipStream_t stream) {
    const float* U0_re = (const float*)d_in[0];
    const float* U0_im = (const float*)d_in[1];
    const float* xs    = (const float*)d_in[2];
    const float* V_re  = (const float*)d_in[3];
    const float* V_im  = (const float*)d_in[4];
    float* out = (float*)d_out;

    const int nb = in_sizes[2] / 3;
    const int grid = (nb + BPB - 1) / BPB;
    sun_diffuse_kernel<<<grid, 256, 0, stream>>>(U0_re, U0_im, xs, V_re, V_im, out, nb);
}

// Round 6
// 32.785 us; speedup vs baseline: 1.4624x; 1.2220x over previous
//
#include <hip/hip_runtime.h>

// One thread per batch (3x3 complex). 256 batches/block, 4 waves, wave-private
// LDS, zero __syncthreads(). Single 1152-f32 buffer per wave reused three
// times (V -> U0 -> out) relying on in-wave DS ordering (proven R2/R5).
// xs is loaded directly per-lane (3 dwords, no staging). NOTHING is held in
// registers across a compute phase (R5 lesson: reg prefetch -> scratch spill).
// LDS 18432 B/block + <=72 VGPR -> ~28 waves/CU (vs 16 in the 25.8us version).

#define BPB 256

__global__ __launch_bounds__(256, 7)
void sun_diffuse_kernel(const float* __restrict__ U0_re, const float* __restrict__ U0_im,
                        const float* __restrict__ xs,
                        const float* __restrict__ V_re, const float* __restrict__ V_im,
                        float* __restrict__ out, int nb)
{
    __shared__ __align__(16) float smem[4][1152];   // per-wave: 64 batches

    const int tid  = threadIdx.x;
    const int w    = tid >> 6;
    const int lane = tid & 63;
    const int wb0  = blockIdx.x * BPB + w * 64;      // first batch of this wave
    const int nw   = min(max(nb - wb0, 0), 64);      // batches this wave owns
    const bool full = (nw == 64);

    float* S  = smem[w];
    float* sA = S;                                   // re-part plane (576 f32)
    float* sB = S + 576;                             // im-part plane (576 f32)
    float4* sA4 = reinterpret_cast<float4*>(sA);
    float4* sB4 = reinterpret_cast<float4*>(sB);

    // ---- stage V (coalesced float4: 144 per plane; wb0*36 B is 16B-aligned) ----
    if (full) {
        const float4* gVr = reinterpret_cast<const float4*>(V_re + (size_t)wb0 * 9);
        const float4* gVi = reinterpret_cast<const float4*>(V_im + (size_t)wb0 * 9);
#pragma unroll
        for (int r = 0; r < 3; ++r) {
            const int i = lane + r * 64;             // 144 = 2*64 + 16
            if (i < 144) { sA4[i] = gVr[i]; sB4[i] = gVi[i]; }
        }
    } else {
        for (int i = lane; i < nw * 9; i += 64) {
            sA[i] = V_re[(size_t)wb0 * 9 + i];
            sB[i] = V_im[(size_t)wb0 * 9 + i];
        }
    }

    // ---- phase 1: E = V diag(e^{ix}) V^H ----
    float Er[9], Ei[9];
    if (lane < nw) {
        const size_t xb = (size_t)(wb0 + lane) * 3;
        float pr[3], pi[3];
#pragma unroll
        for (int k = 0; k < 3; ++k) {
            float s, c;
            __sincosf(xs[xb + k], &s, &c);           // direct per-lane xs load
            pr[k] = c; pi[k] = s;
        }
        float vr[9], vi[9];
#pragma unroll
        for (int m = 0; m < 9; ++m) { vr[m] = sA[lane * 9 + m]; vi[m] = sB[lane * 9 + m]; }
#pragma unroll
        for (int i = 0; i < 3; ++i) {
#pragma unroll
            for (int j = 0; j < 3; ++j) {
                float er = 0.f, ei = 0.f;
#pragma unroll
                for (int k = 0; k < 3; ++k) {
                    float wr = pr[k] * vr[i * 3 + k] - pi[k] * vi[i * 3 + k];
                    float wi = pr[k] * vi[i * 3 + k] + pi[k] * vr[i * 3 + k];
                    er += wr * vr[j * 3 + k] + wi * vi[j * 3 + k];
                    ei += wi * vr[j * 3 + k] - wr * vi[j * 3 + k];
                }
                Er[i * 3 + j] = er; Ei[i * 3 + j] = ei;
            }
        }
    }

    // ---- restage U0 into the SAME buffer (transient reg pass-through only;
    //      WAR vs the V ds_reads above is safe: per-wave LDS ops are in-order) ----
    if (full) {
        const float4* gUr = reinterpret_cast<const float4*>(U0_re + (size_t)wb0 * 9);
        const float4* gUi = reinterpret_cast<const float4*>(U0_im + (size_t)wb0 * 9);
#pragma unroll
        for (int r = 0; r < 3; ++r) {
            const int i = lane + r * 64;
            if (i < 144) { sA4[i] = gUr[i]; sB4[i] = gUi[i]; }
        }
    } else {
        for (int i = lane; i < nw * 9; i += 64) {
            sA[i] = U0_re[(size_t)wb0 * 9 + i];
            sB[i] = U0_im[(size_t)wb0 * 9 + i];
        }
    }

    // ---- phase 2: Ut = E @ U0, stage interleaved re/im into same buffer ----
    if (lane < nw) {
        float ur[9], ui[9];
#pragma unroll
        for (int m = 0; m < 9; ++m) { ur[m] = sA[lane * 9 + m]; ui[m] = sB[lane * 9 + m]; }
        float outr[9], outi[9];
#pragma unroll
        for (int i = 0; i < 3; ++i) {
#pragma unroll
            for (int j = 0; j < 3; ++j) {
                float r = 0.f, im = 0.f;
#pragma unroll
                for (int k = 0; k < 3; ++k) {
                    r  += Er[i * 3 + k] * ur[k * 3 + j] - Ei[i * 3 + k] * ui[k * 3 + j];
                    im += Er[i * 3 + k] * ui[k * 3 + j] + Ei[i * 3 + k] * ur[k * 3 + j];
                }
                outr[i * 3 + j] = r; outi[i * 3 + j] = im;
            }
        }
#pragma unroll
        for (int m = 0; m < 9; ++m) {
            S[lane * 18 + 2 * m]     = outr[m];
            S[lane * 18 + 2 * m + 1] = outi[m];
        }
    }

    // ---- coalesced flush: 1152 f32 = 288 float4 (wb0*72 B is 16B-aligned) ----
    if (full) {
        float4* gO = reinterpret_cast<float4*>(out + (size_t)wb0 * 18);
        const float4* s = reinterpret_cast<const float4*>(S);
#pragma unroll
        for (int r = 0; r < 5; ++r) {
            const int i = lane + r * 64;             // 288 = 4*64 + 32
            if (i < 288) gO[i] = s[i];
        }
    } else if (nw > 0) {
        for (int i = lane; i < nw * 18; i += 64) out[(size_t)wb0 * 18 + i] = S[i];
    }
}

extern "C" void kernel_launch(void* const* d_in, const int* in_sizes, int n_in,
                              void* d_out, int out_size, void* d_ws, size_t ws_size,
                              hipStream_t stream) {
    const float* U0_re = (const float*)d_in[0];
    const float* U0_im = (const float*)d_in[1];
    const float* xs    = (const float*)d_in[2];
    const float* V_re  = (const float*)d_in[3];
    const float* V_im  = (const float*)d_in[4];
    float* out = (float*)d_out;

    const int nb = in_sizes[2] / 3;
    const int grid = (nb + BPB - 1) / BPB;
    sun_diffuse_kernel<<<grid, 256, 0, stream>>>(U0_re, U0_im, xs, V_re, V_im, out, nb);
}